// Round 5
// baseline (291.068 us; speedup 1.0000x reference)
//
#include <hip/hip_runtime.h>

// GCN 2-layer forward for MI355X.
// out = D^-1/2 (A+I) D^-1/2 (X W) + b, twice, relu between.
// g = (X W) * dinv ; tmp[c] = g[c] + sum_{e: col_e=c} g[row_e] ; out = tmp*dinv + b.
// R2: CSR gather (no fp32 atomics). R3: parallel 3-phase scan.
// R4: g stored bf16 (halves gather traffic).
// R5: GEMM via MFMA with split-bf16 (hi+lo) A and W: 3 MFMAs give ~fp32 accuracy
//     at matrix-core rate. No LDS: A-frags from registers, B-frags from
//     pre-transposed/split W tables (L2-resident).

constexpr int KD = 128;  // inner dim of both GEMMs (Fin = Fh = 128)

using short8  = __attribute__((ext_vector_type(8))) short;
using float4v = __attribute__((ext_vector_type(4))) float;

// ---------------- bf16 helpers (storage = ushort, math = fp32) ----------------

__device__ __forceinline__ unsigned short f2bf(float f) {
    unsigned int u = __float_as_uint(f);
    u = (u + 0x7fffu + ((u >> 16) & 1u)) >> 16;  // round-to-nearest-even
    return (unsigned short)u;
}

__device__ __forceinline__ float2 bfpair(unsigned int u) {
    float2 f;
    f.x = __uint_as_float(u << 16);          // low short = first feature
    f.y = __uint_as_float(u & 0xffff0000u);  // high short = second feature
    return f;
}

// split x = hi + lo (both bf16); subtraction is exact, |err| ~ 2^-17 |x|
__device__ __forceinline__ void bfsplit(float x, unsigned short& h, unsigned short& l) {
    h = f2bf(x);
    float fh = __uint_as_float((unsigned int)h << 16);
    l = f2bf(x - fh);
}

// ---------------- CSR build ----------------

__global__ __launch_bounds__(256) void hist_zero(int* cnt, int N) {
    int i = blockIdx.x * 256 + threadIdx.x;
    if (i < N) cnt[i] = 0;
}

__global__ __launch_bounds__(256) void hist(const int* __restrict__ col, int* cnt, int E) {
    int i = blockIdx.x * 256 + threadIdx.x;
    if (i < E) atomicAdd(&cnt[col[i]], 1);
}

// Phase 1: per-block (1024 elems) sum of cnt -> blockSums[b]
__global__ __launch_bounds__(256) void block_reduce(const int* __restrict__ cnt,
                                                    int* __restrict__ blockSums, int N) {
    __shared__ int wsum[4];
    int base = blockIdx.x * 1024 + threadIdx.x * 4;
    int s = 0;
#pragma unroll
    for (int j = 0; j < 4; ++j) {
        int i = base + j;
        if (i < N) s += cnt[i];
    }
    for (int off = 32; off > 0; off >>= 1) s += __shfl_down(s, off, 64);
    int wave = threadIdx.x >> 6;
    if ((threadIdx.x & 63) == 0) wsum[wave] = s;
    __syncthreads();
    if (threadIdx.x == 0)
        blockSums[blockIdx.x] = wsum[0] + wsum[1] + wsum[2] + wsum[3];
}

// Phase 2: single wave exclusive-scans blockSums (NB <= 64) in place; rowptr[N]=E.
__global__ __launch_bounds__(64) void scan_block_sums(int* blockSums, int NB,
                                                      int* rowptr, int N, int E) {
    int lane = threadIdx.x;
    int v = (lane < NB) ? blockSums[lane] : 0;
    int s = v;
    for (int off = 1; off < 64; off <<= 1) {
        int t = __shfl_up(s, off, 64);
        if (lane >= off) s += t;
    }
    if (lane < NB) blockSums[lane] = s - v;  // exclusive
    if (lane == 0) rowptr[N] = E;
}

// Phase 3: per-block exclusive scan of 1024 cnt, + block offset; write rowptr/cursor/dinv.
__global__ __launch_bounds__(256) void block_scan_apply(const int* __restrict__ cnt,
                                                        const int* __restrict__ blockSums,
                                                        int* __restrict__ rowptr,
                                                        int* __restrict__ cursor,
                                                        float* __restrict__ dinv, int N) {
    __shared__ int tsum[256];
    int base = blockIdx.x * 1024 + threadIdx.x * 4;
    int v[4];
    int tot = 0;
#pragma unroll
    for (int j = 0; j < 4; ++j) {
        int i = base + j;
        v[j] = (i < N) ? cnt[i] : 0;
        tot += v[j];
    }
    tsum[threadIdx.x] = tot;
    __syncthreads();
    for (int off = 1; off < 256; off <<= 1) {
        int t = (threadIdx.x >= off) ? tsum[threadIdx.x - off] : 0;
        __syncthreads();
        tsum[threadIdx.x] += t;
        __syncthreads();
    }
    int p = blockSums[blockIdx.x] + tsum[threadIdx.x] - tot;  // exclusive start
#pragma unroll
    for (int j = 0; j < 4; ++j) {
        int i = base + j;
        if (i < N) {
            rowptr[i] = p;
            cursor[i] = p;
            dinv[i] = rsqrtf(1.0f + (float)v[j]);
        }
        p += v[j];
    }
}

__global__ __launch_bounds__(256) void fill_csr(const int* __restrict__ row,
                                                const int* __restrict__ col,
                                                int* cursor, int* __restrict__ srow, int E) {
    int i = blockIdx.x * 256 + threadIdx.x;
    if (i < E) {
        int slot = atomicAdd(&cursor[col[i]], 1);
        srow[slot] = row[i];
    }
}

// ---------------- W preprocess: transpose + split to bf16 hi/lo ----------------
// Wt_hi[n][k] = bf16(W[k][n]); Wt_lo[n][k] = bf16(W[k][n] - hi).  K = 128.
template <int FOUT>
__global__ void conv_w(const float* __restrict__ W,
                       unsigned short* __restrict__ Wth,
                       unsigned short* __restrict__ Wtl) {
    int k = blockIdx.x;      // 0..127
    int n = threadIdx.x;     // 0..FOUT-1
    float w = W[k * FOUT + n];
    unsigned short h, l;
    bfsplit(w, h, l);
    Wth[n * KD + k] = h;
    Wtl[n * KD + k] = l;
}

// ---------------- MFMA GEMM: G[n,:] = bf16( dinv[n] * (X[n,:] @ W) ) ----------
// One wave per 16-row tile. A-frags built in registers from fp32 X (hi/lo split);
// B-frags loaded from Wt_hi/Wt_lo (L2-resident). acc = AhBh + AlBh + AhBl.
// Verified gfx950 16x16x32 layouts: A[m=lane&15][k=(lane>>4)*8+j],
// B[k=(lane>>4)*8+j][n=lane&15], C/D row=(lane>>4)*4+reg, col=lane&15.
template <int FOUT>
__global__ __launch_bounds__(256) void gemm_mfma(const float* __restrict__ X,
                                                 const unsigned short* __restrict__ Wth,
                                                 const unsigned short* __restrict__ Wtl,
                                                 const float* __restrict__ dinv,
                                                 unsigned short* __restrict__ G, int N) {
    constexpr int NT = FOUT / 16;  // col tiles
    int wave = threadIdx.x >> 6;
    int lane = threadIdx.x & 63;
    int row0 = (blockIdx.x * 4 + wave) * 16;
    if (row0 >= N) return;
    int m = lane & 15;
    int quad = lane >> 4;

    float4v acc[NT];
#pragma unroll
    for (int ct = 0; ct < NT; ++ct) acc[ct] = (float4v){0.f, 0.f, 0.f, 0.f};

    const float* xrow = X + (size_t)(row0 + m) * KD + quad * 8;

#pragma unroll
    for (int ks = 0; ks < 4; ++ks) {
        float4 xa = *(const float4*)(xrow + ks * 32);
        float4 xb = *(const float4*)(xrow + ks * 32 + 4);
        float xs[8] = {xa.x, xa.y, xa.z, xa.w, xb.x, xb.y, xb.z, xb.w};
        short8 ah, al;
#pragma unroll
        for (int j = 0; j < 8; ++j) {
            unsigned short h, l;
            bfsplit(xs[j], h, l);
            ah[j] = (short)h;
            al[j] = (short)l;
        }
        int koff = ks * 32 + quad * 8;
#pragma unroll
        for (int ct = 0; ct < NT; ++ct) {
            const unsigned short* wb = Wth + (size_t)(ct * 16 + m) * KD + koff;
            const unsigned short* wl = Wtl + (size_t)(ct * 16 + m) * KD + koff;
            short8 bh = *(const short8*)wb;
            short8 bl = *(const short8*)wl;
            acc[ct] = __builtin_amdgcn_mfma_f32_16x16x32_bf16(ah, bh, acc[ct], 0, 0, 0);
            acc[ct] = __builtin_amdgcn_mfma_f32_16x16x32_bf16(al, bh, acc[ct], 0, 0, 0);
            acc[ct] = __builtin_amdgcn_mfma_f32_16x16x32_bf16(ah, bl, acc[ct], 0, 0, 0);
        }
    }

    // epilogue: row = row0 + quad*4 + r, col = ct*16 + m
#pragma unroll
    for (int r = 0; r < 4; ++r) {
        int row = row0 + quad * 4 + r;
        float s = dinv[row];
#pragma unroll
        for (int ct = 0; ct < NT; ++ct) {
            G[(size_t)row * FOUT + ct * 16 + m] = f2bf(acc[ct][r] * s);
        }
    }
}

// ---------------- CSR gather + finalize (fused), bf16 operand ----------------
// F=128: one wave per node, lane holds 2 features (ushort2 = 1 dword load/row).
template <bool RELU>
__global__ __launch_bounds__(256) void gather128(const int* __restrict__ rowptr,
                                                 const int* __restrict__ srow,
                                                 const unsigned int* __restrict__ G,  // bf16x2
                                                 const float* __restrict__ dinv,
                                                 const float* __restrict__ bias,
                                                 float* __restrict__ O, int N) {
    int node = (blockIdx.x * 256 + threadIdx.x) >> 6;
    int lane = threadIdx.x & 63;
    if (node >= N) return;
    int beg = rowptr[node];
    int end = rowptr[node + 1];

    float2 s0 = bfpair(G[(size_t)node * 64 + lane]);  // self-loop
    float ax = s0.x, ay = s0.y;

    int e = beg;
    for (; e + 3 < end; e += 4) {
        int r0 = srow[e], r1 = srow[e + 1], r2 = srow[e + 2], r3 = srow[e + 3];
        float2 v0 = bfpair(G[(size_t)r0 * 64 + lane]);
        float2 v1 = bfpair(G[(size_t)r1 * 64 + lane]);
        float2 v2 = bfpair(G[(size_t)r2 * 64 + lane]);
        float2 v3 = bfpair(G[(size_t)r3 * 64 + lane]);
        ax += (v0.x + v1.x) + (v2.x + v3.x);
        ay += (v0.y + v1.y) + (v2.y + v3.y);
    }
    for (; e < end; ++e) {
        float2 v = bfpair(G[(size_t)srow[e] * 64 + lane]);
        ax += v.x;
        ay += v.y;
    }
    float s = dinv[node];
    float2 bv = ((const float2*)bias)[lane];
    float ox = ax * s + bv.x;
    float oy = ay * s + bv.y;
    if (RELU) { ox = fmaxf(ox, 0.f); oy = fmaxf(oy, 0.f); }
    ((float2*)O)[(size_t)node * 64 + lane] = make_float2(ox, oy);
}

// F=64: half-wave per node (32 lanes x ushort2 = 128B row), 2 nodes per wave.
template <bool RELU>
__global__ __launch_bounds__(256) void gather64(const int* __restrict__ rowptr,
                                                const int* __restrict__ srow,
                                                const unsigned int* __restrict__ G,  // bf16x2
                                                const float* __restrict__ dinv,
                                                const float* __restrict__ bias,
                                                float* __restrict__ O, int N) {
    int tid = blockIdx.x * 256 + threadIdx.x;
    int node = tid >> 5;          // half-wave per node
    int lane = threadIdx.x & 31;
    if (node >= N) return;
    int beg = rowptr[node];
    int end = rowptr[node + 1];

    float2 s0 = bfpair(G[(size_t)node * 32 + lane]);  // self-loop
    float ax = s0.x, ay = s0.y;

    int e = beg;
    for (; e + 3 < end; e += 4) {
        int r0 = srow[e], r1 = srow[e + 1], r2 = srow[e + 2], r3 = srow[e + 3];
        float2 v0 = bfpair(G[(size_t)r0 * 32 + lane]);
        float2 v1 = bfpair(G[(size_t)r1 * 32 + lane]);
        float2 v2 = bfpair(G[(size_t)r2 * 32 + lane]);
        float2 v3 = bfpair(G[(size_t)r3 * 32 + lane]);
        ax += (v0.x + v1.x) + (v2.x + v3.x);
        ay += (v0.y + v1.y) + (v2.y + v3.y);
    }
    for (; e < end; ++e) {
        float2 v = bfpair(G[(size_t)srow[e] * 32 + lane]);
        ax += v.x;
        ay += v.y;
    }
    float s = dinv[node];
    float2 bv = ((const float2*)bias)[lane];
    float ox = ax * s + bv.x;
    float oy = ay * s + bv.y;
    if (RELU) { ox = fmaxf(ox, 0.f); oy = fmaxf(oy, 0.f); }
    ((float2*)O)[(size_t)node * 32 + lane] = make_float2(ox, oy);
}

extern "C" void kernel_launch(void* const* d_in, const int* in_sizes, int n_in,
                              void* d_out, int out_size, void* d_ws, size_t ws_size,
                              hipStream_t stream) {
    const float* x  = (const float*)d_in[0];
    const int*   ei = (const int*)d_in[1];   // int32
    const float* W1 = (const float*)d_in[2];
    const float* b1 = (const float*)d_in[3];
    const float* W2 = (const float*)d_in[4];
    const float* b2 = (const float*)d_in[5];
    float* out = (float*)d_out;

    int N = in_sizes[0] / 128;
    int E = in_sizes[1] / 2;
    const int* row = ei;       // edge_index[0]
    const int* col = ei + E;   // edge_index[1]

    // Workspace layout (all regions written before read each call)
    char* ws = (char*)d_ws;
    float* dinv   = (float*)(ws + 0x000000);             // 200 KB
    int*   cnt    = (int*)  (ws + 0x040000);             // 200 KB
    int*   rowptr = (int*)  (ws + 0x080000);             // 200 KB + 4
    int*   cursor = (int*)  (ws + 0x0C0000);             // 200 KB
    int*   bsums  = (int*)  (ws + 0x0FC000);             // 49 ints
    int*   srow   = (int*)  (ws + 0x100000);             // 3.2 MB
    unsigned short* g1 = (unsigned short*)(ws + 0x440000);   // N*128 bf16 = 12.8 MB
    unsigned short* wth1 = (unsigned short*)(ws + 0x10C0000);  // 32 KB
    unsigned short* wtl1 = (unsigned short*)(ws + 0x10D0000);  // 32 KB
    unsigned short* wth2 = (unsigned short*)(ws + 0x10E0000);  // 16 KB
    unsigned short* wtl2 = (unsigned short*)(ws + 0x10F0000);  // 16 KB
    float* h2     = (float*)(ws + 0x1200000);            // N*128 fp32 = 25.6 MB
    unsigned short* g2 = (unsigned short*)(ws + 0x2C00000);  // N*64 bf16 = 6.4 MB

    int NB_SCAN = (N + 1023) / 1024;  // 49 for N=50000 (<=64 for phase-2 wave scan)

    int nb;
    // CSR build (shared by both layers) + dinv
    nb = (N + 255) / 256; hist_zero<<<nb, 256, 0, stream>>>(cnt, N);
    nb = (E + 255) / 256; hist<<<nb, 256, 0, stream>>>(col, cnt, E);
    block_reduce<<<NB_SCAN, 256, 0, stream>>>(cnt, bsums, N);
    scan_block_sums<<<1, 64, 0, stream>>>(bsums, NB_SCAN, rowptr, N, E);
    block_scan_apply<<<NB_SCAN, 256, 0, stream>>>(cnt, bsums, rowptr, cursor, dinv, N);
    nb = (E + 255) / 256; fill_csr<<<nb, 256, 0, stream>>>(row, col, cursor, srow, E);

    // W preprocess (tiny)
    conv_w<128><<<128, 128, 0, stream>>>(W1, wth1, wtl1);
    conv_w<64><<<128, 64, 0, stream>>>(W2, wth2, wtl2);

    // ---- layer 1 (F=128, relu) ----
    nb = (N + 63) / 64;  // 4 waves/block, 16 rows/wave
    gemm_mfma<128><<<nb, 256, 0, stream>>>(x, wth1, wtl1, dinv, g1, N);
    nb = (N + 3) / 4;    // one wave per node
    gather128<true><<<nb, 256, 0, stream>>>(rowptr, srow, (const unsigned int*)g1,
                                            dinv, b1, h2, N);

    // ---- layer 2 (F=64, no relu) ----
    nb = (N + 63) / 64;
    gemm_mfma<64><<<nb, 256, 0, stream>>>(h2, wth2, wtl2, dinv, g2, N);
    nb = (N + 7) / 8;    // half-wave per node
    gather64<false><<<nb, 256, 0, stream>>>(rowptr, srow, (const unsigned int*)g2,
                                            dinv, b2, out, N);
}

// Round 6
// 268.498 us; speedup vs baseline: 1.0841x; 1.0841x over previous
//
#include <hip/hip_runtime.h>

// GCN 2-layer forward for MI355X.
// out = D^-1/2 (A+I) D^-1/2 (X W) + b, twice, relu between.
// g = (X W) * dinv ; tmp[c] = g[c] + sum_{e: col_e=c} g[row_e] ; out = tmp*dinv + b.
// R2: CSR gather (no fp32 atomics). R3: parallel 3-phase scan.
// R4: g stored bf16 (halves gather traffic).
// R5: GEMM via MFMA with split-bf16 (hi+lo): 3 MFMAs ~ fp32 accuracy.
// R6: bucket edges by col>>8 before hist/fill -> scattered 4B stores become
//     L2-local runs (was 52MB HBM write-amp on a 3.2MB buffer, 51us).

constexpr int KD = 128;  // inner dim of both GEMMs (Fin = Fh = 128)
constexpr int CHUNK = 4096;  // edges per block in bucket passes

using short8  = __attribute__((ext_vector_type(8))) short;
using float4v = __attribute__((ext_vector_type(4))) float;

// ---------------- bf16 helpers (storage = ushort, math = fp32) ----------------

__device__ __forceinline__ unsigned short f2bf(float f) {
    unsigned int u = __float_as_uint(f);
    u = (u + 0x7fffu + ((u >> 16) & 1u)) >> 16;  // round-to-nearest-even
    return (unsigned short)u;
}

__device__ __forceinline__ float2 bfpair(unsigned int u) {
    float2 f;
    f.x = __uint_as_float(u << 16);          // low short = first feature
    f.y = __uint_as_float(u & 0xffff0000u);  // high short = second feature
    return f;
}

// split x = hi + lo (both bf16); subtraction is exact, |err| ~ 2^-17 |x|
__device__ __forceinline__ void bfsplit(float x, unsigned short& h, unsigned short& l) {
    h = f2bf(x);
    float fh = __uint_as_float((unsigned int)h << 16);
    l = f2bf(x - fh);
}

// ---------------- edge bucketing (by col >> 8) ----------------

__global__ __launch_bounds__(256) void zero_all(int* cnt, int N, int* bcnt) {
    int i = blockIdx.x * 256 + threadIdx.x;
    if (i < N) cnt[i] = 0;
    if (blockIdx.x == 0) bcnt[threadIdx.x] = 0;
}

__global__ __launch_bounds__(256) void bucket_count(const int* __restrict__ col,
                                                    int* __restrict__ bcnt, int E) {
    __shared__ int lh[256];
    lh[threadIdx.x] = 0;
    __syncthreads();
    int base = blockIdx.x * CHUNK;
#pragma unroll
    for (int r = 0; r < CHUNK / 256; ++r) {
        int e = base + r * 256 + threadIdx.x;
        if (e < E) atomicAdd(&lh[col[e] >> 8], 1);
    }
    __syncthreads();
    int v = lh[threadIdx.x];
    if (v) atomicAdd(&bcnt[threadIdx.x], v);
}

// 1 block: exclusive scan of bcnt[256] -> gcur (bucket write cursors)
__global__ __launch_bounds__(256) void bucket_scan(const int* __restrict__ bcnt,
                                                   int* __restrict__ gcur) {
    __shared__ int s[256];
    int v = bcnt[threadIdx.x];
    s[threadIdx.x] = v;
    __syncthreads();
    for (int off = 1; off < 256; off <<= 1) {
        int t = (threadIdx.x >= off) ? s[threadIdx.x - off] : 0;
        __syncthreads();
        s[threadIdx.x] += t;
        __syncthreads();
    }
    gcur[threadIdx.x] = s[threadIdx.x] - v;  // exclusive
}

__global__ __launch_bounds__(256) void bucket_scatter(const int* __restrict__ row,
                                                      const int* __restrict__ col,
                                                      int* gcur,
                                                      int* __restrict__ bcol,
                                                      int* __restrict__ brow, int E) {
    __shared__ int lh[256];
    __shared__ int lbase[256];
    lh[threadIdx.x] = 0;
    __syncthreads();
    int base = blockIdx.x * CHUNK;
#pragma unroll
    for (int r = 0; r < CHUNK / 256; ++r) {
        int e = base + r * 256 + threadIdx.x;
        if (e < E) atomicAdd(&lh[col[e] >> 8], 1);
    }
    __syncthreads();
    int c0 = lh[threadIdx.x];
    lbase[threadIdx.x] = c0 ? atomicAdd(&gcur[threadIdx.x], c0) : 0;
    __syncthreads();
    lh[threadIdx.x] = 0;  // reuse as local running offset
    __syncthreads();
#pragma unroll
    for (int r = 0; r < CHUNK / 256; ++r) {
        int e = base + r * 256 + threadIdx.x;
        if (e < E) {
            int c = col[e];
            int b = c >> 8;
            int slot = lbase[b] + atomicAdd(&lh[b], 1);
            bcol[slot] = c;
            brow[slot] = row[e];
        }
    }
}

// bucket-major: atomics localized to ~784B cnt windows
__global__ __launch_bounds__(256) void hist_nodes(const int* __restrict__ bcol,
                                                  int* cnt, int E) {
    int i = blockIdx.x * 256 + threadIdx.x;
    if (i < E) atomicAdd(&cnt[bcol[i]], 1);
}

// bucket-major: cursor atomics + srow stores localized to ~12.5KB windows
__global__ __launch_bounds__(256) void fill_csr2(const int* __restrict__ bcol,
                                                 const int* __restrict__ brow,
                                                 int* cursor, int* __restrict__ srow, int E) {
    int i = blockIdx.x * 256 + threadIdx.x;
    if (i < E) {
        int slot = atomicAdd(&cursor[bcol[i]], 1);
        srow[slot] = brow[i];
    }
}

// ---------------- rowptr scan (3-phase) ----------------

__global__ __launch_bounds__(256) void block_reduce(const int* __restrict__ cnt,
                                                    int* __restrict__ blockSums, int N) {
    __shared__ int wsum[4];
    int base = blockIdx.x * 1024 + threadIdx.x * 4;
    int s = 0;
#pragma unroll
    for (int j = 0; j < 4; ++j) {
        int i = base + j;
        if (i < N) s += cnt[i];
    }
    for (int off = 32; off > 0; off >>= 1) s += __shfl_down(s, off, 64);
    int wave = threadIdx.x >> 6;
    if ((threadIdx.x & 63) == 0) wsum[wave] = s;
    __syncthreads();
    if (threadIdx.x == 0)
        blockSums[blockIdx.x] = wsum[0] + wsum[1] + wsum[2] + wsum[3];
}

__global__ __launch_bounds__(64) void scan_block_sums(int* blockSums, int NB,
                                                      int* rowptr, int N, int E) {
    int lane = threadIdx.x;
    int v = (lane < NB) ? blockSums[lane] : 0;
    int s = v;
    for (int off = 1; off < 64; off <<= 1) {
        int t = __shfl_up(s, off, 64);
        if (lane >= off) s += t;
    }
    if (lane < NB) blockSums[lane] = s - v;  // exclusive
    if (lane == 0) rowptr[N] = E;
}

__global__ __launch_bounds__(256) void block_scan_apply(const int* __restrict__ cnt,
                                                        const int* __restrict__ blockSums,
                                                        int* __restrict__ rowptr,
                                                        int* __restrict__ cursor,
                                                        float* __restrict__ dinv, int N) {
    __shared__ int tsum[256];
    int base = blockIdx.x * 1024 + threadIdx.x * 4;
    int v[4];
    int tot = 0;
#pragma unroll
    for (int j = 0; j < 4; ++j) {
        int i = base + j;
        v[j] = (i < N) ? cnt[i] : 0;
        tot += v[j];
    }
    tsum[threadIdx.x] = tot;
    __syncthreads();
    for (int off = 1; off < 256; off <<= 1) {
        int t = (threadIdx.x >= off) ? tsum[threadIdx.x - off] : 0;
        __syncthreads();
        tsum[threadIdx.x] += t;
        __syncthreads();
    }
    int p = blockSums[blockIdx.x] + tsum[threadIdx.x] - tot;  // exclusive start
#pragma unroll
    for (int j = 0; j < 4; ++j) {
        int i = base + j;
        if (i < N) {
            rowptr[i] = p;
            cursor[i] = p;
            dinv[i] = rsqrtf(1.0f + (float)v[j]);
        }
        p += v[j];
    }
}

// ---------------- W preprocess (both layers, one launch) ----------------
// Wt_hi[n][k] = bf16(W[k][n]); Wt_lo = bf16(residual).  K = 128 for both.
__global__ void conv_w_both(const float* __restrict__ W1,
                            unsigned short* __restrict__ Wth1,
                            unsigned short* __restrict__ Wtl1,
                            const float* __restrict__ W2,
                            unsigned short* __restrict__ Wth2,
                            unsigned short* __restrict__ Wtl2) {
    int k = blockIdx.x & 127;
    int n = threadIdx.x;
    if (blockIdx.x < 128) {
        float w = W1[k * 128 + n];
        unsigned short h, l;
        bfsplit(w, h, l);
        Wth1[n * KD + k] = h;
        Wtl1[n * KD + k] = l;
    } else if (n < 64) {
        float w = W2[k * 64 + n];
        unsigned short h, l;
        bfsplit(w, h, l);
        Wth2[n * KD + k] = h;
        Wtl2[n * KD + k] = l;
    }
}

// ---------------- MFMA GEMM: G[n,:] = bf16( dinv[n] * (X[n,:] @ W) ) ----------
// One wave per 16-row tile. A-frags built in registers from fp32 X (hi/lo split);
// B-frags from Wt_hi/Wt_lo (L2-resident). acc = AhBh + AlBh + AhBl.
template <int FOUT>
__global__ __launch_bounds__(256) void gemm_mfma(const float* __restrict__ X,
                                                 const unsigned short* __restrict__ Wth,
                                                 const unsigned short* __restrict__ Wtl,
                                                 const float* __restrict__ dinv,
                                                 unsigned short* __restrict__ G, int N) {
    constexpr int NT = FOUT / 16;  // col tiles
    int wave = threadIdx.x >> 6;
    int lane = threadIdx.x & 63;
    int row0 = (blockIdx.x * 4 + wave) * 16;
    if (row0 >= N) return;
    int m = lane & 15;
    int quad = lane >> 4;

    float4v acc[NT];
#pragma unroll
    for (int ct = 0; ct < NT; ++ct) acc[ct] = (float4v){0.f, 0.f, 0.f, 0.f};

    const float* xrow = X + (size_t)(row0 + m) * KD + quad * 8;

#pragma unroll
    for (int ks = 0; ks < 4; ++ks) {
        float4 xa = *(const float4*)(xrow + ks * 32);
        float4 xb = *(const float4*)(xrow + ks * 32 + 4);
        float xs[8] = {xa.x, xa.y, xa.z, xa.w, xb.x, xb.y, xb.z, xb.w};
        short8 ah, al;
#pragma unroll
        for (int j = 0; j < 8; ++j) {
            unsigned short h, l;
            bfsplit(xs[j], h, l);
            ah[j] = (short)h;
            al[j] = (short)l;
        }
        int koff = ks * 32 + quad * 8;
#pragma unroll
        for (int ct = 0; ct < NT; ++ct) {
            const unsigned short* wb = Wth + (size_t)(ct * 16 + m) * KD + koff;
            const unsigned short* wl = Wtl + (size_t)(ct * 16 + m) * KD + koff;
            short8 bh = *(const short8*)wb;
            short8 bl = *(const short8*)wl;
            acc[ct] = __builtin_amdgcn_mfma_f32_16x16x32_bf16(ah, bh, acc[ct], 0, 0, 0);
            acc[ct] = __builtin_amdgcn_mfma_f32_16x16x32_bf16(al, bh, acc[ct], 0, 0, 0);
            acc[ct] = __builtin_amdgcn_mfma_f32_16x16x32_bf16(ah, bl, acc[ct], 0, 0, 0);
        }
    }

    // epilogue: row = row0 + quad*4 + r, col = ct*16 + m
#pragma unroll
    for (int r = 0; r < 4; ++r) {
        int row = row0 + quad * 4 + r;
        float s = dinv[row];
#pragma unroll
        for (int ct = 0; ct < NT; ++ct) {
            G[(size_t)row * FOUT + ct * 16 + m] = f2bf(acc[ct][r] * s);
        }
    }
}

// ---------------- CSR gather + finalize (fused), bf16 operand ----------------

template <bool RELU>
__global__ __launch_bounds__(256) void gather128(const int* __restrict__ rowptr,
                                                 const int* __restrict__ srow,
                                                 const unsigned int* __restrict__ G,  // bf16x2
                                                 const float* __restrict__ dinv,
                                                 const float* __restrict__ bias,
                                                 float* __restrict__ O, int N) {
    int node = (blockIdx.x * 256 + threadIdx.x) >> 6;
    int lane = threadIdx.x & 63;
    if (node >= N) return;
    int beg = rowptr[node];
    int end = rowptr[node + 1];

    float2 s0 = bfpair(G[(size_t)node * 64 + lane]);  // self-loop
    float ax = s0.x, ay = s0.y;

    int e = beg;
    for (; e + 3 < end; e += 4) {
        int r0 = srow[e], r1 = srow[e + 1], r2 = srow[e + 2], r3 = srow[e + 3];
        float2 v0 = bfpair(G[(size_t)r0 * 64 + lane]);
        float2 v1 = bfpair(G[(size_t)r1 * 64 + lane]);
        float2 v2 = bfpair(G[(size_t)r2 * 64 + lane]);
        float2 v3 = bfpair(G[(size_t)r3 * 64 + lane]);
        ax += (v0.x + v1.x) + (v2.x + v3.x);
        ay += (v0.y + v1.y) + (v2.y + v3.y);
    }
    for (; e < end; ++e) {
        float2 v = bfpair(G[(size_t)srow[e] * 64 + lane]);
        ax += v.x;
        ay += v.y;
    }
    float s = dinv[node];
    float2 bv = ((const float2*)bias)[lane];
    float ox = ax * s + bv.x;
    float oy = ay * s + bv.y;
    if (RELU) { ox = fmaxf(ox, 0.f); oy = fmaxf(oy, 0.f); }
    ((float2*)O)[(size_t)node * 64 + lane] = make_float2(ox, oy);
}

template <bool RELU>
__global__ __launch_bounds__(256) void gather64(const int* __restrict__ rowptr,
                                                const int* __restrict__ srow,
                                                const unsigned int* __restrict__ G,  // bf16x2
                                                const float* __restrict__ dinv,
                                                const float* __restrict__ bias,
                                                float* __restrict__ O, int N) {
    int tid = blockIdx.x * 256 + threadIdx.x;
    int node = tid >> 5;          // half-wave per node
    int lane = threadIdx.x & 31;
    if (node >= N) return;
    int beg = rowptr[node];
    int end = rowptr[node + 1];

    float2 s0 = bfpair(G[(size_t)node * 32 + lane]);  // self-loop
    float ax = s0.x, ay = s0.y;

    int e = beg;
    for (; e + 3 < end; e += 4) {
        int r0 = srow[e], r1 = srow[e + 1], r2 = srow[e + 2], r3 = srow[e + 3];
        float2 v0 = bfpair(G[(size_t)r0 * 32 + lane]);
        float2 v1 = bfpair(G[(size_t)r1 * 32 + lane]);
        float2 v2 = bfpair(G[(size_t)r2 * 32 + lane]);
        float2 v3 = bfpair(G[(size_t)r3 * 32 + lane]);
        ax += (v0.x + v1.x) + (v2.x + v3.x);
        ay += (v0.y + v1.y) + (v2.y + v3.y);
    }
    for (; e < end; ++e) {
        float2 v = bfpair(G[(size_t)srow[e] * 32 + lane]);
        ax += v.x;
        ay += v.y;
    }
    float s = dinv[node];
    float2 bv = ((const float2*)bias)[lane];
    float ox = ax * s + bv.x;
    float oy = ay * s + bv.y;
    if (RELU) { ox = fmaxf(ox, 0.f); oy = fmaxf(oy, 0.f); }
    ((float2*)O)[(size_t)node * 32 + lane] = make_float2(ox, oy);
}

extern "C" void kernel_launch(void* const* d_in, const int* in_sizes, int n_in,
                              void* d_out, int out_size, void* d_ws, size_t ws_size,
                              hipStream_t stream) {
    const float* x  = (const float*)d_in[0];
    const int*   ei = (const int*)d_in[1];   // int32
    const float* W1 = (const float*)d_in[2];
    const float* b1 = (const float*)d_in[3];
    const float* W2 = (const float*)d_in[4];
    const float* b2 = (const float*)d_in[5];
    float* out = (float*)d_out;

    int N = in_sizes[0] / 128;
    int E = in_sizes[1] / 2;
    const int* row = ei;       // edge_index[0]
    const int* col = ei + E;   // edge_index[1]

    // Workspace layout (all regions written before read each call)
    char* ws = (char*)d_ws;
    float* dinv   = (float*)(ws + 0x000000);             // 200 KB
    int*   cnt    = (int*)  (ws + 0x040000);             // 200 KB
    int*   rowptr = (int*)  (ws + 0x080000);             // 200 KB + 4
    int*   cursor = (int*)  (ws + 0x0C0000);             // 200 KB
    int*   bcnt   = (int*)  (ws + 0x0F8000);             // 1 KB
    int*   gcur   = (int*)  (ws + 0x0F9000);             // 1 KB
    int*   bsums  = (int*)  (ws + 0x0FC000);             // 49 ints
    int*   srow   = (int*)  (ws + 0x100000);             // 3.2 MB
    unsigned short* g1 = (unsigned short*)(ws + 0x440000);     // 12.8 MB
    unsigned short* wth1 = (unsigned short*)(ws + 0x10C0000);  // 32 KB
    unsigned short* wtl1 = (unsigned short*)(ws + 0x10D0000);  // 32 KB
    unsigned short* wth2 = (unsigned short*)(ws + 0x10E0000);  // 16 KB
    unsigned short* wtl2 = (unsigned short*)(ws + 0x10F0000);  // 16 KB
    float* h2     = (float*)(ws + 0x1200000);            // 25.6 MB
    unsigned short* g2 = (unsigned short*)(ws + 0x2C00000);    // 6.4 MB
    // bcol/brow overlap h2: consumed (fill_csr2) before h2 is first written (gather128)
    int*   bcol   = (int*)  (ws + 0x1200000);            // 3.2 MB
    int*   brow   = (int*)  (ws + 0x1540000);            // 3.2 MB

    int NB_SCAN = (N + 1023) / 1024;     // 49 (<=64 for phase-2 wave scan)
    int NB_BKT  = (E + CHUNK - 1) / CHUNK;

    int nb;
    // ---- edge bucketing + CSR build + dinv ----
    nb = (N + 255) / 256; zero_all<<<nb, 256, 0, stream>>>(cnt, N, bcnt);
    bucket_count<<<NB_BKT, 256, 0, stream>>>(col, bcnt, E);
    bucket_scan<<<1, 256, 0, stream>>>(bcnt, gcur);
    bucket_scatter<<<NB_BKT, 256, 0, stream>>>(row, col, gcur, bcol, brow, E);
    nb = (E + 255) / 256; hist_nodes<<<nb, 256, 0, stream>>>(bcol, cnt, E);
    block_reduce<<<NB_SCAN, 256, 0, stream>>>(cnt, bsums, N);
    scan_block_sums<<<1, 64, 0, stream>>>(bsums, NB_SCAN, rowptr, N, E);
    block_scan_apply<<<NB_SCAN, 256, 0, stream>>>(cnt, bsums, rowptr, cursor, dinv, N);
    nb = (E + 255) / 256; fill_csr2<<<nb, 256, 0, stream>>>(bcol, brow, cursor, srow, E);

    // W preprocess (tiny, one launch)
    conv_w_both<<<256, 128, 0, stream>>>(W1, wth1, wtl1, W2, wth2, wtl2);

    // ---- layer 1 (F=128, relu) ----
    nb = (N + 63) / 64;  // 4 waves/block, 16 rows/wave
    gemm_mfma<128><<<nb, 256, 0, stream>>>(x, wth1, wtl1, dinv, g1, N);
    nb = (N + 3) / 4;    // one wave per node
    gather128<true><<<nb, 256, 0, stream>>>(rowptr, srow, (const unsigned int*)g1,
                                            dinv, b1, h2, N);

    // ---- layer 2 (F=64, no relu) ----
    nb = (N + 63) / 64;
    gemm_mfma<64><<<nb, 256, 0, stream>>>(h2, wth2, wtl2, dinv, g2, N);
    nb = (N + 7) / 8;    // half-wave per node
    gather64<false><<<nb, 256, 0, stream>>>(rowptr, srow, (const unsigned int*)g2,
                                            dinv, b2, out, N);
}

// Round 8
// 234.354 us; speedup vs baseline: 1.2420x; 1.1457x over previous
//
#include <hip/hip_runtime.h>

// GCN 2-layer forward for MI355X.
// out = D^-1/2 (A+I) D^-1/2 (X W) + b, twice, relu between.
// g = (X W) * dinv ; tmp[c] = g[c] + sum_{e: col_e=c} g[row_e] ; out = tmp*dinv + b.
// R2: CSR gather (no fp32 atomics). R3: parallel scan. R4: g stored bf16.
// R5: GEMM via MFMA split-bf16 (hi+lo), ~fp32 accuracy at matrix rate.
// R6: bucket edges by col>>8 (kills 64B-line write-amp on scattered stores).
// R7: consolidated CSR build (slack buckets, rowptr/dinv/srow in one kernel).
// R8: fix R7 bucket overflow: only 196 buckets populated (cols < 50000), so
//     mean/bucket = 4096 not 3125 -> BCAP 4096 overflowed ~half the buckets.
//     BCAP = 6144 (mean + 32 sigma).

constexpr int KD = 128;      // inner dim of both GEMMs (Fin = Fh = 128)
constexpr int CHUNK = 4096;  // edges per block in scatter pass
constexpr int BCAP = 6144;   // slack capacity per bucket (mean 4096, sigma ~64)

using short8  = __attribute__((ext_vector_type(8))) short;
using float4v = __attribute__((ext_vector_type(4))) float;

// ---------------- bf16 helpers (storage = ushort, math = fp32) ----------------

__device__ __forceinline__ unsigned short f2bf(float f) {
    unsigned int u = __float_as_uint(f);
    u = (u + 0x7fffu + ((u >> 16) & 1u)) >> 16;  // round-to-nearest-even
    return (unsigned short)u;
}

__device__ __forceinline__ float2 bfpair(unsigned int u) {
    float2 f;
    f.x = __uint_as_float(u << 16);          // low short = first feature
    f.y = __uint_as_float(u & 0xffff0000u);  // high short = second feature
    return f;
}

// split x = hi + lo (both bf16); subtraction is exact, |err| ~ 2^-17 |x|
__device__ __forceinline__ void bfsplit(float x, unsigned short& h, unsigned short& l) {
    h = f2bf(x);
    float fh = __uint_as_float((unsigned int)h << 16);
    l = f2bf(x - fh);
}

// ---------------- CSR build ----------------

// gcur[b] = b*BCAP (write cursor into slack buffer)
__global__ __launch_bounds__(256) void init_gcur(int* gcur) {
    gcur[threadIdx.x] = threadIdx.x * BCAP;
}

// Edge scatter into slack buckets: per-block LDS hist -> one global cursor bump
// per (block,bucket) -> locally-ordered writes. No count prepass needed.
__global__ __launch_bounds__(256) void bucket_scatter(const int* __restrict__ row,
                                                      const int* __restrict__ col,
                                                      int* gcur,
                                                      int* __restrict__ bcol,
                                                      int* __restrict__ brow, int E) {
    __shared__ int lh[256];
    __shared__ int lbase[256];
    lh[threadIdx.x] = 0;
    __syncthreads();
    int base = blockIdx.x * CHUNK;
#pragma unroll
    for (int r = 0; r < CHUNK / 256; ++r) {
        int e = base + r * 256 + threadIdx.x;
        if (e < E) atomicAdd(&lh[col[e] >> 8], 1);
    }
    __syncthreads();
    int c0 = lh[threadIdx.x];
    lbase[threadIdx.x] = c0 ? atomicAdd(&gcur[threadIdx.x], c0) : 0;
    __syncthreads();
    lh[threadIdx.x] = 0;  // reuse as local running offset
    __syncthreads();
#pragma unroll
    for (int r = 0; r < CHUNK / 256; ++r) {
        int e = base + r * 256 + threadIdx.x;
        if (e < E) {
            int c = col[e];
            int b = c >> 8;
            int slot = lbase[b] + atomicAdd(&lh[b], 1);
            bcol[slot] = c;
            brow[slot] = row[e];
        }
    }
}

// 1 block: bucket counts (gcur[b]-b*BCAP) -> exclusive scan -> bstart; rowptr[N]=E.
__global__ __launch_bounds__(256) void bucket_scan(const int* __restrict__ gcur,
                                                   int* __restrict__ bstart,
                                                   int* rowptr, int N, int E) {
    __shared__ int s[256];
    int v = gcur[threadIdx.x] - threadIdx.x * BCAP;
    s[threadIdx.x] = v;
    __syncthreads();
    for (int off = 1; off < 256; off <<= 1) {
        int t = (threadIdx.x >= off) ? s[threadIdx.x - off] : 0;
        __syncthreads();
        s[threadIdx.x] += t;
        __syncthreads();
    }
    bstart[threadIdx.x] = s[threadIdx.x] - v;  // exclusive
    if (threadIdx.x == 0) rowptr[N] = E;
}

// One block per bucket: LDS hist of 256 nodes -> LDS scan -> rowptr/dinv/srow.
// Bucket-major + node-within-bucket order IS global CSR order (bstart[b] = rowptr[256b]).
__global__ __launch_bounds__(256) void bucket_csr(const int* __restrict__ bcol,
                                                  const int* __restrict__ brow,
                                                  const int* __restrict__ gcur,
                                                  const int* __restrict__ bstart,
                                                  int* __restrict__ rowptr,
                                                  float* __restrict__ dinv,
                                                  int* __restrict__ srow, int N) {
    __shared__ int lh[256];
    __shared__ int s[256];
    __shared__ int lcur[256];
    int b = blockIdx.x;
    int nE = gcur[b] - b * BCAP;
    int base = b * BCAP;
    lh[threadIdx.x] = 0;
    __syncthreads();
    for (int i = threadIdx.x; i < nE; i += 256)
        atomicAdd(&lh[bcol[base + i] & 255], 1);
    __syncthreads();
    int v = lh[threadIdx.x];
    s[threadIdx.x] = v;
    __syncthreads();
    for (int off = 1; off < 256; off <<= 1) {
        int t = (threadIdx.x >= off) ? s[threadIdx.x - off] : 0;
        __syncthreads();
        s[threadIdx.x] += t;
        __syncthreads();
    }
    int myStart = bstart[b] + s[threadIdx.x] - v;  // exclusive
    int node = (b << 8) + threadIdx.x;
    if (node < N) {
        rowptr[node] = myStart;
        dinv[node] = rsqrtf(1.0f + (float)v);
    }
    lcur[threadIdx.x] = myStart;
    __syncthreads();
    for (int i = threadIdx.x; i < nE; i += 256) {
        int c = bcol[base + i] & 255;
        int slot = atomicAdd(&lcur[c], 1);
        srow[slot] = brow[base + i];
    }
}

// ---------------- W preprocess (both layers, one launch) ----------------
// Wt_hi[n][k] = bf16(W[k][n]); Wt_lo = bf16(residual).  K = 128 for both.
__global__ void conv_w_both(const float* __restrict__ W1,
                            unsigned short* __restrict__ Wth1,
                            unsigned short* __restrict__ Wtl1,
                            const float* __restrict__ W2,
                            unsigned short* __restrict__ Wth2,
                            unsigned short* __restrict__ Wtl2) {
    int k = blockIdx.x & 127;
    int n = threadIdx.x;
    if (blockIdx.x < 128) {
        float w = W1[k * 128 + n];
        unsigned short h, l;
        bfsplit(w, h, l);
        Wth1[n * KD + k] = h;
        Wtl1[n * KD + k] = l;
    } else if (n < 64) {
        float w = W2[k * 64 + n];
        unsigned short h, l;
        bfsplit(w, h, l);
        Wth2[n * KD + k] = h;
        Wtl2[n * KD + k] = l;
    }
}

// ---------------- MFMA GEMM: G[n,:] = bf16( dinv[n] * (X[n,:] @ W) ) ----------
// One wave per 16-row tile. A-frags built in registers from fp32 X (hi/lo split);
// B-frags from Wt_hi/Wt_lo (L2-resident). acc = AhBh + AlBh + AhBl.
template <int FOUT>
__global__ __launch_bounds__(256) void gemm_mfma(const float* __restrict__ X,
                                                 const unsigned short* __restrict__ Wth,
                                                 const unsigned short* __restrict__ Wtl,
                                                 const float* __restrict__ dinv,
                                                 unsigned short* __restrict__ G, int N) {
    constexpr int NT = FOUT / 16;  // col tiles
    int wave = threadIdx.x >> 6;
    int lane = threadIdx.x & 63;
    int row0 = (blockIdx.x * 4 + wave) * 16;
    if (row0 >= N) return;
    int m = lane & 15;
    int quad = lane >> 4;

    float4v acc[NT];
#pragma unroll
    for (int ct = 0; ct < NT; ++ct) acc[ct] = (float4v){0.f, 0.f, 0.f, 0.f};

    const float* xrow = X + (size_t)(row0 + m) * KD + quad * 8;

#pragma unroll
    for (int ks = 0; ks < 4; ++ks) {
        float4 xa = *(const float4*)(xrow + ks * 32);
        float4 xb = *(const float4*)(xrow + ks * 32 + 4);
        float xs[8] = {xa.x, xa.y, xa.z, xa.w, xb.x, xb.y, xb.z, xb.w};
        short8 ah, al;
#pragma unroll
        for (int j = 0; j < 8; ++j) {
            unsigned short h, l;
            bfsplit(xs[j], h, l);
            ah[j] = (short)h;
            al[j] = (short)l;
        }
        int koff = ks * 32 + quad * 8;
#pragma unroll
        for (int ct = 0; ct < NT; ++ct) {
            const unsigned short* wb = Wth + (size_t)(ct * 16 + m) * KD + koff;
            const unsigned short* wl = Wtl + (size_t)(ct * 16 + m) * KD + koff;
            short8 bh = *(const short8*)wb;
            short8 bl = *(const short8*)wl;
            acc[ct] = __builtin_amdgcn_mfma_f32_16x16x32_bf16(ah, bh, acc[ct], 0, 0, 0);
            acc[ct] = __builtin_amdgcn_mfma_f32_16x16x32_bf16(al, bh, acc[ct], 0, 0, 0);
            acc[ct] = __builtin_amdgcn_mfma_f32_16x16x32_bf16(ah, bl, acc[ct], 0, 0, 0);
        }
    }

    // epilogue: row = row0 + quad*4 + r, col = ct*16 + m
#pragma unroll
    for (int r = 0; r < 4; ++r) {
        int row = row0 + quad * 4 + r;
        float s = dinv[row];
#pragma unroll
        for (int ct = 0; ct < NT; ++ct) {
            G[(size_t)row * FOUT + ct * 16 + m] = f2bf(acc[ct][r] * s);
        }
    }
}

// ---------------- CSR gather + finalize (fused), bf16 operand ----------------

template <bool RELU>
__global__ __launch_bounds__(256) void gather128(const int* __restrict__ rowptr,
                                                 const int* __restrict__ srow,
                                                 const unsigned int* __restrict__ G,  // bf16x2
                                                 const float* __restrict__ dinv,
                                                 const float* __restrict__ bias,
                                                 float* __restrict__ O, int N) {
    int node = (blockIdx.x * 256 + threadIdx.x) >> 6;
    int lane = threadIdx.x & 63;
    if (node >= N) return;
    int beg = rowptr[node];
    int end = rowptr[node + 1];

    float2 s0 = bfpair(G[(size_t)node * 64 + lane]);  // self-loop
    float ax = s0.x, ay = s0.y;

    int e = beg;
    for (; e + 3 < end; e += 4) {
        int r0 = srow[e], r1 = srow[e + 1], r2 = srow[e + 2], r3 = srow[e + 3];
        float2 v0 = bfpair(G[(size_t)r0 * 64 + lane]);
        float2 v1 = bfpair(G[(size_t)r1 * 64 + lane]);
        float2 v2 = bfpair(G[(size_t)r2 * 64 + lane]);
        float2 v3 = bfpair(G[(size_t)r3 * 64 + lane]);
        ax += (v0.x + v1.x) + (v2.x + v3.x);
        ay += (v0.y + v1.y) + (v2.y + v3.y);
    }
    for (; e < end; ++e) {
        float2 v = bfpair(G[(size_t)srow[e] * 64 + lane]);
        ax += v.x;
        ay += v.y;
    }
    float s = dinv[node];
    float2 bv = ((const float2*)bias)[lane];
    float ox = ax * s + bv.x;
    float oy = ay * s + bv.y;
    if (RELU) { ox = fmaxf(ox, 0.f); oy = fmaxf(oy, 0.f); }
    ((float2*)O)[(size_t)node * 64 + lane] = make_float2(ox, oy);
}

template <bool RELU>
__global__ __launch_bounds__(256) void gather64(const int* __restrict__ rowptr,
                                                const int* __restrict__ srow,
                                                const unsigned int* __restrict__ G,  // bf16x2
                                                const float* __restrict__ dinv,
                                                const float* __restrict__ bias,
                                                float* __restrict__ O, int N) {
    int tid = blockIdx.x * 256 + threadIdx.x;
    int node = tid >> 5;          // half-wave per node
    int lane = threadIdx.x & 31;
    if (node >= N) return;
    int beg = rowptr[node];
    int end = rowptr[node + 1];

    float2 s0 = bfpair(G[(size_t)node * 32 + lane]);  // self-loop
    float ax = s0.x, ay = s0.y;

    int e = beg;
    for (; e + 3 < end; e += 4) {
        int r0 = srow[e], r1 = srow[e + 1], r2 = srow[e + 2], r3 = srow[e + 3];
        float2 v0 = bfpair(G[(size_t)r0 * 32 + lane]);
        float2 v1 = bfpair(G[(size_t)r1 * 32 + lane]);
        float2 v2 = bfpair(G[(size_t)r2 * 32 + lane]);
        float2 v3 = bfpair(G[(size_t)r3 * 32 + lane]);
        ax += (v0.x + v1.x) + (v2.x + v3.x);
        ay += (v0.y + v1.y) + (v2.y + v3.y);
    }
    for (; e < end; ++e) {
        float2 v = bfpair(G[(size_t)srow[e] * 32 + lane]);
        ax += v.x;
        ay += v.y;
    }
    float s = dinv[node];
    float2 bv = ((const float2*)bias)[lane];
    float ox = ax * s + bv.x;
    float oy = ay * s + bv.y;
    if (RELU) { ox = fmaxf(ox, 0.f); oy = fmaxf(oy, 0.f); }
    ((float2*)O)[(size_t)node * 32 + lane] = make_float2(ox, oy);
}

extern "C" void kernel_launch(void* const* d_in, const int* in_sizes, int n_in,
                              void* d_out, int out_size, void* d_ws, size_t ws_size,
                              hipStream_t stream) {
    const float* x  = (const float*)d_in[0];
    const int*   ei = (const int*)d_in[1];   // int32
    const float* W1 = (const float*)d_in[2];
    const float* b1 = (const float*)d_in[3];
    const float* W2 = (const float*)d_in[4];
    const float* b2 = (const float*)d_in[5];
    float* out = (float*)d_out;

    int N = in_sizes[0] / 128;
    int E = in_sizes[1] / 2;
    const int* row = ei;       // edge_index[0]
    const int* col = ei + E;   // edge_index[1]

    // Workspace layout (all regions written before read each call)
    char* ws = (char*)d_ws;
    float* dinv   = (float*)(ws + 0x000000);             // 200 KB
    int*   rowptr = (int*)  (ws + 0x080000);             // 200 KB + 4
    int*   gcur   = (int*)  (ws + 0x0F9000);             // 1 KB
    int*   bstart = (int*)  (ws + 0x0FA000);             // 1 KB
    int*   srow   = (int*)  (ws + 0x100000);             // 3.2 MB
    unsigned short* g1 = (unsigned short*)(ws + 0x440000);     // 12.8 MB
    unsigned short* wth1 = (unsigned short*)(ws + 0x10C0000);  // 32 KB
    unsigned short* wtl1 = (unsigned short*)(ws + 0x10D0000);  // 32 KB
    unsigned short* wth2 = (unsigned short*)(ws + 0x10E0000);  // 16 KB
    unsigned short* wtl2 = (unsigned short*)(ws + 0x10F0000);  // 16 KB
    float* h2     = (float*)(ws + 0x1200000);            // 25.6 MB
    unsigned short* g2 = (unsigned short*)(ws + 0x2C00000);    // 6.4 MB
    // Slack bucket buffers (256 x BCAP ints = 6.29 MB each) overlap h2's region:
    // consumed by bucket_csr before gather128 first writes h2.
    int*   bcol   = (int*)  (ws + 0x1200000);            // 6.29 MB
    int*   brow   = (int*)  (ws + 0x1800000);            // 6.29 MB (ends 0x1E00000)

    int NB_BKT  = (E + CHUNK - 1) / CHUNK;
    int NBUCKET = (N + 255) / 256;   // 196

    // ---- CSR build: 4 launches ----
    init_gcur<<<1, 256, 0, stream>>>(gcur);
    bucket_scatter<<<NB_BKT, 256, 0, stream>>>(row, col, gcur, bcol, brow, E);
    bucket_scan<<<1, 256, 0, stream>>>(gcur, bstart, rowptr, N, E);
    bucket_csr<<<NBUCKET, 256, 0, stream>>>(bcol, brow, gcur, bstart, rowptr, dinv, srow, N);

    // W preprocess (tiny, one launch)
    conv_w_both<<<256, 128, 0, stream>>>(W1, wth1, wtl1, W2, wth2, wtl2);

    int nb;
    // ---- layer 1 (F=128, relu) ----
    nb = (N + 63) / 64;  // 4 waves/block, 16 rows/wave
    gemm_mfma<128><<<nb, 256, 0, stream>>>(x, wth1, wtl1, dinv, g1, N);
    nb = (N + 3) / 4;    // one wave per node
    gather128<true><<<nb, 256, 0, stream>>>(rowptr, srow, (const unsigned int*)g1,
                                            dinv, b1, h2, N);

    // ---- layer 2 (F=64, no relu) ----
    nb = (N + 63) / 64;
    gemm_mfma<64><<<nb, 256, 0, stream>>>(h2, wth2, wtl2, dinv, g2, N);
    nb = (N + 7) / 8;    // half-wave per node
    gather64<false><<<nb, 256, 0, stream>>>(rowptr, srow, (const unsigned int*)g2,
                                            dinv, b2, out, N);
}